// Round 6
// baseline (216.197 us; speedup 1.0000x reference)
//
#include <hip/hip_runtime.h>

#define NQ 10000
#define BS 2
#define NV 19560
#define NH 8
#define HD 32
#define EMB 256

typedef __attribute__((ext_vector_type(8))) short bf16x8;
typedef __attribute__((ext_vector_type(4))) float f32x4;
typedef __attribute__((ext_vector_type(4))) short s16x4;

__device__ __forceinline__ unsigned short f2bf(float x) {
    unsigned u = __float_as_uint(x);
    u += 0x7FFFu + ((u >> 16) & 1u);       // RNE
    return (unsigned short)(u >> 16);
}

// ---------------------------------------------------------------------------
// Transpose weights into Bt[n][k] bf16 (rows 0-255 W_val, 256-511 W_off,
// 512-639 W_attn) + concat biases. Tiny one-shot kernel. [proven]
// ---------------------------------------------------------------------------
__global__ __launch_bounds__(256) void convert_W(
    const float* __restrict__ Wv, const float* __restrict__ Wo,
    const float* __restrict__ Wa, const float* __restrict__ bv,
    const float* __restrict__ bo, const float* __restrict__ ba,
    ushort* __restrict__ Bt, float* __restrict__ bias) {
    int n = blockIdx.x;      // 0..639
    int k = threadIdx.x;     // 0..255
    float x;
    if (n < 256)       x = Wv[k * 256 + n];
    else if (n < 512)  x = Wo[k * 256 + (n - 256)];
    else               x = Wa[k * 128 + (n - 512)];
    Bt[n * 256 + k] = f2bf(x);
    if (k == 0)
        bias[n] = (n < 256) ? bv[n] : (n < 512) ? bo[n - 256] : ba[n - 512];
}

// ---------------------------------------------------------------------------
// Fused GEMM. ROUND-15: m93 ladder step applied to the PROVEN r9/r13
// structure — tile 64x128 -> 128x128, SAME 2-barrier k-loop, SAME staging
// style, SAME epilogue formula. 4 waves in 2x2 grid, each 64x64 (4x4 accs):
// 32 MFMAs per barrier-pair (was 8) -> 4x amortization of the barrier drain
// (the measured r9 stall); grid 2163 -> 1083 blocks. Parameter change on a
// verified template (two-lane discipline), NOT a new sync structure
// (r10/r11/r12 all proved those regress). T1 bijective remap recomputed:
// value 612 = 8*76+4, query 471 = 8*58+7 (m204 split form).
// ---------------------------------------------------------------------------
__global__ __launch_bounds__(256) void gemm_fused(
    const float* __restrict__ value, const float* __restrict__ query,
    const float* __restrict__ qpos, const ushort* __restrict__ Bt,
    const float* __restrict__ bias,
    ushort* __restrict__ Cv, float* __restrict__ C0, float* __restrict__ C1)
{
    __shared__ short As[128][40], Bhs[128][40];  // pad 32->40, 20480 B

    const int tid = threadIdx.x;

    // ---- T1: XCD-aware bijective remap (m204 form, new section sizes) ----
    const int bid0 = blockIdx.x;
    int bid;
    if (bid0 < 612) {                      // value: 612 = 8*76 + 4
        int xcd = bid0 & 7, idx = bid0 >> 3;
        bid = (xcd < 4) ? (xcd * 77 + idx)
                        : (4 * 77 + (xcd - 4) * 76 + idx);
    } else {                               // query: 471 = 8*58 + 7
        int q = bid0 - 612;
        int xcd = q & 7, idx = q >> 3;
        int orig = (xcd < 7) ? (xcd * 59 + idx)
                             : (7 * 59 + (xcd - 7) * 58 + idx);
        bid = 612 + orig;
    }

    bool isval; int mblk, npan;
    if (bid < 612) { isval = true;  mblk = bid >> 1; npan = bid & 1; }
    else { int q = bid - 612; isval = false; mblk = q / 3; npan = q % 3; }

    const int M  = isval ? (BS * NV) : (BS * NQ);
    const int m0 = mblk * 128;
    const int n0 = npan * 128;
    const int nbase = (isval ? 0 : 256) + n0;

    const float* A = isval ? value : query;

    // A staging: thread t -> row t>>1 (0..127), k-half (t&1)*16 (16 of 32 k)
    const int arow = tid >> 1;
    const int acol = (tid & 1) * 16;
    const bool aval = (m0 + arow) < M;
    const float* Ap  = A    + (size_t)(m0 + arow) * 256 + acol;
    const float* A2p = qpos + (size_t)(m0 + arow) * 256 + acol;
    // B staging: thread t -> row t>>1 (0..127), k-half (t&1)*16 (16 of 32 k)
    const int brow = tid >> 1;
    const int bcol = (tid & 1) * 16;
    const ushort* Bp = Bt + (size_t)(nbase + brow) * 256 + bcol;

    const int lane = tid & 63, wave = tid >> 6;
    const int wrow = (wave >> 1) * 64, wcol = (wave & 1) * 64;
    const int lr = lane & 15, quad = lane >> 4, lk = quad * 8;

    f32x4 acc[4][4] = {};

    for (int k0 = 0; k0 < 256; k0 += 32) {
        // ---- A: fp32 (+qpos) -> bf16 staged to LDS (proven form, 16/thr) --
        {
            f32x4 v0 = {}, v1 = {}, v2 = {}, v3 = {};
            if (aval) {
                v0 = *(const f32x4*)(Ap + k0);
                v1 = *(const f32x4*)(Ap + k0 + 4);
                v2 = *(const f32x4*)(Ap + k0 + 8);
                v3 = *(const f32x4*)(Ap + k0 + 12);
                if (!isval) {
                    v0 += *(const f32x4*)(A2p + k0);
                    v1 += *(const f32x4*)(A2p + k0 + 4);
                    v2 += *(const f32x4*)(A2p + k0 + 8);
                    v3 += *(const f32x4*)(A2p + k0 + 12);
                }
            }
            bf16x8 t0, t1;
            #pragma unroll
            for (int e = 0; e < 4; e++) {
                t0[e]     = (short)f2bf(v0[e]);
                t0[e + 4] = (short)f2bf(v1[e]);
                t1[e]     = (short)f2bf(v2[e]);
                t1[e + 4] = (short)f2bf(v3[e]);
            }
            *(bf16x8*)&As[arow][acol]     = t0;
            *(bf16x8*)&As[arow][acol + 8] = t1;
        }
        // ---- B: bf16 vector copy, BOTH halves (16 shorts/thread) ----
        *(bf16x8*)&Bhs[brow][bcol]     = *(const bf16x8*)(Bp + k0);
        *(bf16x8*)&Bhs[brow][bcol + 8] = *(const bf16x8*)(Bp + k0 + 8);
        __syncthreads();

        bf16x8 af[4], bhf[4];
        #pragma unroll
        for (int i = 0; i < 4; i++)
            af[i] = *(const bf16x8*)&As[wrow + i * 16 + lr][lk];
        #pragma unroll
        for (int j = 0; j < 4; j++)
            bhf[j] = *(const bf16x8*)&Bhs[wcol + j * 16 + lr][lk];
        #pragma unroll
        for (int i = 0; i < 4; i++)
            #pragma unroll
            for (int j = 0; j < 4; j++)
                acc[i][j] = __builtin_amdgcn_mfma_f32_16x16x32_bf16(af[i], bhf[j], acc[i][j], 0, 0, 0);
        __syncthreads();
    }

    // ---- epilogue (proven mapping; i now 0..3, wrow stride 64) ----
    #pragma unroll
    for (int j = 0; j < 4; j++) {
        int cc = wcol + j * 16 + lr;
        int col = n0 + cc;
        float bb = bias[nbase + cc];
        #pragma unroll
        for (int i = 0; i < 4; i++) {
            int gmb = m0 + wrow + i * 16 + quad * 4;
            #pragma unroll
            for (int r = 0; r < 4; r++) {
                int gm = gmb + r;
                if (gm < M) {
                    float val = acc[i][j][r] + bb;
                    if (isval) {
                        int h = col >> 5, d = col & 31;
                        int b = (gm >= NV) ? 1 : 0;
                        int pix = gm - b * NV;
                        Cv[((size_t)(b * 8 + h) * NV + pix) * 32 + d] = f2bf(val);
                    } else {
                        if (col < 256) C0[(size_t)gm * 256 + col] = val;
                        else           C1[(size_t)gm * 128 + (col - 256)] = val;
                    }
                }
            }
        }
    }
}

// ---------------------------------------------------------------------------
// Fused softmax + location + bilinear gather. [r14 PROVEN, verbatim:
// 16 queries x 1 head per block, (b,h) in low 4 bits -> XCD-local value
// plane in L2. Confirmed: dropped out of top-5 (<55us, was 57).]
// ---------------------------------------------------------------------------
__global__ __launch_bounds__(256) void sample4(
    const ushort* __restrict__ v, const float* __restrict__ off,
    const float* __restrict__ attn, const float* __restrict__ refp,
    float* __restrict__ out)
{
    __shared__ int   s_off[256][5];
    __shared__ float s_w[256][5];

    const int t = threadIdx.x;
    const int combo = blockIdx.x & 15;     // (b, head) -> fixed XCD slot
    const int qgrp  = blockIdx.x >> 4;     // 0..624
    const int b  = combo & 1;
    const int h0 = combo >> 1;             // 0..7

    {
        const int qloc = t >> 4;           // 0..15
        const int lp   = t & 15;
        const int l = lp >> 2, p = lp & 3;
        const size_t bq = (size_t)b * NQ + qgrp * 16 + qloc;

        float logit = attn[bq * 128 + h0 * 16 + lp];
        float mx = logit;
        #pragma unroll
        for (int m = 1; m < 16; m <<= 1) mx = fmaxf(mx, __shfl_xor(mx, m, 16));
        float e = __expf(logit - mx);
        float s = e;
        #pragma unroll
        for (int m = 1; m < 16; m <<= 1) s += __shfl_xor(s, m, 16);
        float w = e / s;

        const float Wf[4] = {160.f, 80.f, 40.f, 20.f};
        const float Hf[4] = {92.f, 46.f, 23.f, 12.f};
        const int   Wi[4] = {160, 80, 40, 20};
        const int   Hi[4] = {92, 46, 23, 12};
        const int   st[4] = {0, 14720, 18400, 19320};

        float ox = off[bq * 256 + h0 * 32 + l * 8 + p * 2];
        float oy = off[bq * 256 + h0 * 32 + l * 8 + p * 2 + 1];
        float rx = refp[bq * 8 + p * 2];
        float ry = refp[bq * 8 + p * 2 + 1];
        float x = rx * Wf[l] + ox - 0.5f;
        float y = ry * Hf[l] + oy - 0.5f;
        float x0f = floorf(x), y0f = floorf(y);
        float wx1 = x - x0f, wy1 = y - y0f;
        float wx0 = 1.f - wx1, wy0 = 1.f - wy1;
        int x0 = (int)x0f, y0 = (int)y0f;
        const int W = Wi[l], H = Hi[l];
        float mx0 = ((unsigned)x0       < (unsigned)W) ? 1.f : 0.f;
        float mx1 = ((unsigned)(x0 + 1) < (unsigned)W) ? 1.f : 0.f;
        float my0 = ((unsigned)y0       < (unsigned)H) ? 1.f : 0.f;
        float my1 = ((unsigned)(y0 + 1) < (unsigned)H) ? 1.f : 0.f;
        int xc0 = min(max(x0, 0), W - 1);
        int xc1 = min(max(x0 + 1, 0), W - 1);
        int yc0 = min(max(y0, 0), H - 1);
        int yc1 = min(max(y0 + 1, 0), H - 1);
        int base = ((b * 8 + h0) * NV + st[l]) * 32;
        s_off[t][0] = base + (yc0 * W + xc0) * 32;
        s_off[t][1] = base + (yc0 * W + xc1) * 32;
        s_off[t][2] = base + (yc1 * W + xc0) * 32;
        s_off[t][3] = base + (yc1 * W + xc1) * 32;
        s_w[t][0] = w * wy0 * wx0 * my0 * mx0;
        s_w[t][1] = w * wy0 * wx1 * my0 * mx1;
        s_w[t][2] = w * wy1 * wx0 * my1 * mx0;
        s_w[t][3] = w * wy1 * wx1 * my1 * mx1;
    }
    __syncthreads();

    const int g = t >> 4;          // 0..15: qloc
    const int lane = t & 15;       // channel pair
    const size_t bq = (size_t)b * NQ + qgrp * 16 + g;
    const int d2 = lane * 2;
    const int pbase = g * 16;      // 16 points of this (q, h0)

    float acc0 = 0.f, acc1 = 0.f, acc2 = 0.f, acc3 = 0.f;
    #pragma unroll
    for (int ib = 0; ib < 4; ib++) {
        int o[16]; float wgt[16];
        #pragma unroll
        for (int pp = 0; pp < 4; pp++) {
            int idx = pbase + ib * 4 + pp;
            #pragma unroll
            for (int c = 0; c < 4; c++) {
                o[pp * 4 + c]   = s_off[idx][c];
                wgt[pp * 4 + c] = s_w[idx][c];
            }
        }
        unsigned u[16];
        #pragma unroll
        for (int j = 0; j < 16; j++)
            u[j] = *(const unsigned*)(v + o[j] + d2);
        #pragma unroll
        for (int j = 0; j < 16; j += 2) {
            acc0 += wgt[j]     * __uint_as_float(u[j] << 16);
            acc1 += wgt[j]     * __uint_as_float(u[j] & 0xffff0000u);
            acc2 += wgt[j + 1] * __uint_as_float(u[j + 1] << 16);
            acc3 += wgt[j + 1] * __uint_as_float(u[j + 1] & 0xffff0000u);
        }
    }
    float2 res = make_float2(acc0 + acc2, acc1 + acc3);
    *(float2*)(out + bq * 256 + h0 * 32 + d2) = res;
}

extern "C" void kernel_launch(void* const* d_in, const int* in_sizes, int n_in,
                              void* d_out, int out_size, void* d_ws, size_t ws_size,
                              hipStream_t stream) {
    const float* query     = (const float*)d_in[0];
    const float* value     = (const float*)d_in[1];
    const float* query_pos = (const float*)d_in[2];
    const float* refp      = (const float*)d_in[3];
    const float* W_val     = (const float*)d_in[4];
    const float* b_val     = (const float*)d_in[5];
    const float* W_off     = (const float*)d_in[6];
    const float* b_off     = (const float*)d_in[7];
    const float* W_attn    = (const float*)d_in[8];
    const float* b_attn    = (const float*)d_in[9];
    float* out = (float*)d_out;

    char* w = (char*)d_ws;
    float*  off    = (float*)w;   w += 20480000;   // 20000 x 256 fp32
    float*  attn   = (float*)w;   w += 10240000;   // 20000 x 128 fp32
    ushort* vp_bf  = (ushort*)w;  w += 20029440;   // planar (b,h,NV,32) bf16
    ushort* Bt     = (ushort*)w;  w += 327680;     // 640 x 256 bf16
    float*  bias_c = (float*)w;   w += 2560;

    convert_W<<<640, 256, 0, stream>>>(W_val, W_off, W_attn, b_val, b_off, b_attn,
                                       Bt, bias_c);

    // one dispatch: value-proj (612 blocks, 128x128 tile) + query-proj (471)
    gemm_fused<<<612 + 471, 256, 0, stream>>>(value, query, query_pos, Bt, bias_c,
                                              vp_bf, off, attn);

    // fused softmax + loc + bilinear sample: 16 queries x 1 head per block,
    // (b,h) in low 4 bits of blockIdx -> XCD-local value plane (1.25MB in L2)
    sample4<<<(BS * NQ / 16) * NH, 256, 0, stream>>>(vp_bf, off, attn, refp, out);
}

// Round 7
// 205.054 us; speedup vs baseline: 1.0543x; 1.0543x over previous
//
#include <hip/hip_runtime.h>

#define NQ 10000
#define BS 2
#define NV 19560
#define NH 8
#define HD 32
#define EMB 256

typedef __attribute__((ext_vector_type(8))) short bf16x8;
typedef __attribute__((ext_vector_type(4))) float f32x4;
typedef __attribute__((ext_vector_type(4))) short s16x4;

__device__ __forceinline__ unsigned short f2bf(float x) {
    unsigned u = __float_as_uint(x);
    u += 0x7FFFu + ((u >> 16) & 1u);       // RNE
    return (unsigned short)(u >> 16);
}

// ---------------------------------------------------------------------------
// Transpose weights into Bt[n][k] bf16 (rows 0-255 W_val, 256-511 W_off,
// 512-639 W_attn) + concat biases. Tiny one-shot kernel. [proven]
// ---------------------------------------------------------------------------
__global__ __launch_bounds__(256) void convert_W(
    const float* __restrict__ Wv, const float* __restrict__ Wo,
    const float* __restrict__ Wa, const float* __restrict__ bv,
    const float* __restrict__ bo, const float* __restrict__ ba,
    ushort* __restrict__ Bt, float* __restrict__ bias) {
    int n = blockIdx.x;      // 0..639
    int k = threadIdx.x;     // 0..255
    float x;
    if (n < 256)       x = Wv[k * 256 + n];
    else if (n < 512)  x = Wo[k * 256 + (n - 256)];
    else               x = Wa[k * 128 + (n - 512)];
    Bt[n * 256 + k] = f2bf(x);
    if (k == 0)
        bias[n] = (n < 256) ? bv[n] : (n < 512) ? bo[n - 256] : ba[n - 512];
}

// ---------------------------------------------------------------------------
// Fused GEMM. [r13 PROVEN, verbatim revert: r9 2-barrier 64x128 body + T1
// XCD bijective remap. Measured 55.2-58.5us across two sessions.
// Post-r15 ledger: 128x128 tile = 85us (occupancy 24%, latency-bound needs
// MORE co-resident blocks, not fewer). Five structural variants all lost to
// this form (r10 119, r11 105, r12 68, r15 85). Do not restructure again.]
// ---------------------------------------------------------------------------
__global__ __launch_bounds__(256) void gemm_fused(
    const float* __restrict__ value, const float* __restrict__ query,
    const float* __restrict__ qpos, const ushort* __restrict__ Bt,
    const float* __restrict__ bias,
    ushort* __restrict__ Cv, float* __restrict__ C0, float* __restrict__ C1)
{
    __shared__ short As[64][40], Bhs[128][40];  // pad 32->40

    const int tid = threadIdx.x;

    // ---- T1: XCD-aware bijective remap [r13 proven] ----
    const int bid0 = blockIdx.x;
    int bid;
    if (bid0 < 1224) {
        bid = (bid0 & 7) * 153 + (bid0 >> 3);              // 1224 = 8*153
    } else {
        int q = bid0 - 1224;                               // 939 = 8*117+3
        int xcd = q & 7, idx = q >> 3;
        int orig = (xcd < 3) ? (xcd * 118 + idx)
                             : (3 * 118 + (xcd - 3) * 117 + idx);
        bid = 1224 + orig;
    }

    bool isval; int mblk, npan;
    if (bid < 1224) { isval = true;  mblk = bid >> 1; npan = bid & 1; }
    else { int q = bid - 1224; isval = false; mblk = q / 3; npan = q % 3; }

    const int M  = isval ? (BS * NV) : (BS * NQ);
    const int m0 = mblk * 64;
    const int n0 = npan * 128;
    const int nbase = (isval ? 0 : 256) + n0;

    const float* A = isval ? value : query;

    // A staging: thread t -> row t>>2 (0..63), k-chunk (t&3)*8 (8 of 32 k)
    const int arow = tid >> 2;
    const int acol = (tid & 3) * 8;
    const bool aval = (m0 + arow) < M;
    const float* Ap  = A    + (size_t)(m0 + arow) * 256 + acol;
    const float* A2p = qpos + (size_t)(m0 + arow) * 256 + acol;
    // B staging: thread t -> row t>>1 (0..127), k-half (t&1)*16 (16 of 32 k)
    const int brow = tid >> 1;
    const int bcol = (tid & 1) * 16;
    const ushort* Bp = Bt + (size_t)(nbase + brow) * 256 + bcol;

    const int lane = tid & 63, wave = tid >> 6;
    const int wrow = (wave >> 1) * 32, wcol = (wave & 1) * 64;
    const int lr = lane & 15, quad = lane >> 4, lk = quad * 8;

    f32x4 acc[2][4] = {};

    for (int k0 = 0; k0 < 256; k0 += 32) {
        // ---- A: fp32 (+qpos) -> bf16 staged to LDS (proven form) ----
        #pragma unroll
        for (int g = 0; g < 2; g++) {
            f32x4 v = {};
            if (aval) {
                v = *(const f32x4*)(Ap + k0 + g * 4);
                if (!isval) v += *(const f32x4*)(A2p + k0 + g * 4);
            }
            s16x4 hh;
            #pragma unroll
            for (int e = 0; e < 4; e++) hh[e] = (short)f2bf(v[e]);
            *(s16x4*)&As[arow][acol + g * 4] = hh;
        }
        // ---- B: bf16 vector copy, BOTH halves (16 shorts/thread) ----
        *(bf16x8*)&Bhs[brow][bcol]     = *(const bf16x8*)(Bp + k0);
        *(bf16x8*)&Bhs[brow][bcol + 8] = *(const bf16x8*)(Bp + k0 + 8);
        __syncthreads();

        bf16x8 af[2], bhf[4];
        #pragma unroll
        for (int i = 0; i < 2; i++)
            af[i] = *(const bf16x8*)&As[wrow + i * 16 + lr][lk];
        #pragma unroll
        for (int j = 0; j < 4; j++)
            bhf[j] = *(const bf16x8*)&Bhs[wcol + j * 16 + lr][lk];
        #pragma unroll
        for (int i = 0; i < 2; i++)
            #pragma unroll
            for (int j = 0; j < 4; j++)
                acc[i][j] = __builtin_amdgcn_mfma_f32_16x16x32_bf16(af[i], bhf[j], acc[i][j], 0, 0, 0);
        __syncthreads();
    }

    // ---- epilogue (proven mapping) ----
    #pragma unroll
    for (int j = 0; j < 4; j++) {
        int cc = wcol + j * 16 + lr;
        int col = n0 + cc;
        float bb = bias[nbase + cc];
        #pragma unroll
        for (int i = 0; i < 2; i++) {
            int gmb = m0 + wrow + i * 16 + quad * 4;
            #pragma unroll
            for (int r = 0; r < 4; r++) {
                int gm = gmb + r;
                if (gm < M) {
                    float val = acc[i][j][r] + bb;
                    if (isval) {
                        int h = col >> 5, d = col & 31;
                        int b = (gm >= NV) ? 1 : 0;
                        int pix = gm - b * NV;
                        Cv[((size_t)(b * 8 + h) * NV + pix) * 32 + d] = f2bf(val);
                    } else {
                        if (col < 256) C0[(size_t)gm * 256 + col] = val;
                        else           C1[(size_t)gm * 128 + (col - 256)] = val;
                    }
                }
            }
        }
    }
}

// ---------------------------------------------------------------------------
// Fused softmax + location + bilinear gather. [r14 PROVEN, verbatim:
// 16 queries x 1 head per block, (b,h) in low 4 bits -> XCD-local value
// plane in L2. Confirmed: FETCH mechanism validated, dropped out of top-5.]
// ---------------------------------------------------------------------------
__global__ __launch_bounds__(256) void sample4(
    const ushort* __restrict__ v, const float* __restrict__ off,
    const float* __restrict__ attn, const float* __restrict__ refp,
    float* __restrict__ out)
{
    __shared__ int   s_off[256][5];
    __shared__ float s_w[256][5];

    const int t = threadIdx.x;
    const int combo = blockIdx.x & 15;     // (b, head) -> fixed XCD slot
    const int qgrp  = blockIdx.x >> 4;     // 0..624
    const int b  = combo & 1;
    const int h0 = combo >> 1;             // 0..7

    {
        const int qloc = t >> 4;           // 0..15
        const int lp   = t & 15;
        const int l = lp >> 2, p = lp & 3;
        const size_t bq = (size_t)b * NQ + qgrp * 16 + qloc;

        float logit = attn[bq * 128 + h0 * 16 + lp];
        float mx = logit;
        #pragma unroll
        for (int m = 1; m < 16; m <<= 1) mx = fmaxf(mx, __shfl_xor(mx, m, 16));
        float e = __expf(logit - mx);
        float s = e;
        #pragma unroll
        for (int m = 1; m < 16; m <<= 1) s += __shfl_xor(s, m, 16);
        float w = e / s;

        const float Wf[4] = {160.f, 80.f, 40.f, 20.f};
        const float Hf[4] = {92.f, 46.f, 23.f, 12.f};
        const int   Wi[4] = {160, 80, 40, 20};
        const int   Hi[4] = {92, 46, 23, 12};
        const int   st[4] = {0, 14720, 18400, 19320};

        float ox = off[bq * 256 + h0 * 32 + l * 8 + p * 2];
        float oy = off[bq * 256 + h0 * 32 + l * 8 + p * 2 + 1];
        float rx = refp[bq * 8 + p * 2];
        float ry = refp[bq * 8 + p * 2 + 1];
        float x = rx * Wf[l] + ox - 0.5f;
        float y = ry * Hf[l] + oy - 0.5f;
        float x0f = floorf(x), y0f = floorf(y);
        float wx1 = x - x0f, wy1 = y - y0f;
        float wx0 = 1.f - wx1, wy0 = 1.f - wy1;
        int x0 = (int)x0f, y0 = (int)y0f;
        const int W = Wi[l], H = Hi[l];
        float mx0 = ((unsigned)x0       < (unsigned)W) ? 1.f : 0.f;
        float mx1 = ((unsigned)(x0 + 1) < (unsigned)W) ? 1.f : 0.f;
        float my0 = ((unsigned)y0       < (unsigned)H) ? 1.f : 0.f;
        float my1 = ((unsigned)(y0 + 1) < (unsigned)H) ? 1.f : 0.f;
        int xc0 = min(max(x0, 0), W - 1);
        int xc1 = min(max(x0 + 1, 0), W - 1);
        int yc0 = min(max(y0, 0), H - 1);
        int yc1 = min(max(y0 + 1, 0), H - 1);
        int base = ((b * 8 + h0) * NV + st[l]) * 32;
        s_off[t][0] = base + (yc0 * W + xc0) * 32;
        s_off[t][1] = base + (yc0 * W + xc1) * 32;
        s_off[t][2] = base + (yc1 * W + xc0) * 32;
        s_off[t][3] = base + (yc1 * W + xc1) * 32;
        s_w[t][0] = w * wy0 * wx0 * my0 * mx0;
        s_w[t][1] = w * wy0 * wx1 * my0 * mx1;
        s_w[t][2] = w * wy1 * wx0 * my1 * mx0;
        s_w[t][3] = w * wy1 * wx1 * my1 * mx1;
    }
    __syncthreads();

    const int g = t >> 4;          // 0..15: qloc
    const int lane = t & 15;       // channel pair
    const size_t bq = (size_t)b * NQ + qgrp * 16 + g;
    const int d2 = lane * 2;
    const int pbase = g * 16;      // 16 points of this (q, h0)

    float acc0 = 0.f, acc1 = 0.f, acc2 = 0.f, acc3 = 0.f;
    #pragma unroll
    for (int ib = 0; ib < 4; ib++) {
        int o[16]; float wgt[16];
        #pragma unroll
        for (int pp = 0; pp < 4; pp++) {
            int idx = pbase + ib * 4 + pp;
            #pragma unroll
            for (int c = 0; c < 4; c++) {
                o[pp * 4 + c]   = s_off[idx][c];
                wgt[pp * 4 + c] = s_w[idx][c];
            }
        }
        unsigned u[16];
        #pragma unroll
        for (int j = 0; j < 16; j++)
            u[j] = *(const unsigned*)(v + o[j] + d2);
        #pragma unroll
        for (int j = 0; j < 16; j += 2) {
            acc0 += wgt[j]     * __uint_as_float(u[j] << 16);
            acc1 += wgt[j]     * __uint_as_float(u[j] & 0xffff0000u);
            acc2 += wgt[j + 1] * __uint_as_float(u[j + 1] << 16);
            acc3 += wgt[j + 1] * __uint_as_float(u[j + 1] & 0xffff0000u);
        }
    }
    float2 res = make_float2(acc0 + acc2, acc1 + acc3);
    *(float2*)(out + bq * 256 + h0 * 32 + d2) = res;
}

extern "C" void kernel_launch(void* const* d_in, const int* in_sizes, int n_in,
                              void* d_out, int out_size, void* d_ws, size_t ws_size,
                              hipStream_t stream) {
    const float* query     = (const float*)d_in[0];
    const float* value     = (const float*)d_in[1];
    const float* query_pos = (const float*)d_in[2];
    const float* refp      = (const float*)d_in[3];
    const float* W_val     = (const float*)d_in[4];
    const float* b_val     = (const float*)d_in[5];
    const float* W_off     = (const float*)d_in[6];
    const float* b_off     = (const float*)d_in[7];
    const float* W_attn    = (const float*)d_in[8];
    const float* b_attn    = (const float*)d_in[9];
    float* out = (float*)d_out;

    char* w = (char*)d_ws;
    float*  off    = (float*)w;   w += 20480000;   // 20000 x 256 fp32
    float*  attn   = (float*)w;   w += 10240000;   // 20000 x 128 fp32
    ushort* vp_bf  = (ushort*)w;  w += 20029440;   // planar (b,h,NV,32) bf16
    ushort* Bt     = (ushort*)w;  w += 327680;     // 640 x 256 bf16
    float*  bias_c = (float*)w;   w += 2560;

    convert_W<<<640, 256, 0, stream>>>(W_val, W_off, W_attn, b_val, b_off, b_attn,
                                       Bt, bias_c);

    // one dispatch: value-proj (1224 blocks) + query-proj (939 blocks)
    gemm_fused<<<1224 + 939, 256, 0, stream>>>(value, query, query_pos, Bt, bias_c,
                                               vp_bf, off, attn);

    // fused softmax + loc + bilinear sample: 16 queries x 1 head per block,
    // (b,h) in low 4 bits of blockIdx -> XCD-local value plane (1.25MB in L2)
    sample4<<<(BS * NQ / 16) * NH, 256, 0, stream>>>(vp_bf, off, attn, refp, out);
}

// Round 8
// 202.474 us; speedup vs baseline: 1.0678x; 1.0127x over previous
//
#include <hip/hip_runtime.h>
#include <hip/hip_fp16.h>

#define NQ 10000
#define BS 2
#define NV 19560
#define NH 8
#define HD 32
#define EMB 256

typedef __attribute__((ext_vector_type(8))) short bf16x8;
typedef __attribute__((ext_vector_type(4))) float f32x4;
typedef __attribute__((ext_vector_type(4))) short s16x4;

__device__ __forceinline__ unsigned short f2bf(float x) {
    unsigned u = __float_as_uint(x);
    u += 0x7FFFu + ((u >> 16) & 1u);       // RNE
    return (unsigned short)(u >> 16);
}

// ---------------------------------------------------------------------------
// Transpose weights into Bt[n][k] bf16 (rows 0-255 W_val, 256-511 W_off,
// 512-639 W_attn) + concat biases. Tiny one-shot kernel. [proven]
// ---------------------------------------------------------------------------
__global__ __launch_bounds__(256) void convert_W(
    const float* __restrict__ Wv, const float* __restrict__ Wo,
    const float* __restrict__ Wa, const float* __restrict__ bv,
    const float* __restrict__ bo, const float* __restrict__ ba,
    ushort* __restrict__ Bt, float* __restrict__ bias) {
    int n = blockIdx.x;      // 0..639
    int k = threadIdx.x;     // 0..255
    float x;
    if (n < 256)       x = Wv[k * 256 + n];
    else if (n < 512)  x = Wo[k * 256 + (n - 256)];
    else               x = Wa[k * 128 + (n - 512)];
    Bt[n * 256 + k] = f2bf(x);
    if (k == 0)
        bias[n] = (n < 256) ? bv[n] : (n < 512) ? bo[n - 256] : ba[n - 512];
}

// ---------------------------------------------------------------------------
// Fused GEMM. [r13 PROVEN body, frozen: r9 2-barrier 64x128 + T1 remap.
// Ledger: r10 119 / r11 105 / r12 68 / r15 85 vs this 56 — do not
// restructure. ROUND-16: ONLY the value-epilogue store changes bf16->fp16
// (sample4 decodes fp16 via fma_mix; f16 is MORE precise than bf16 here).]
// ---------------------------------------------------------------------------
__global__ __launch_bounds__(256) void gemm_fused(
    const float* __restrict__ value, const float* __restrict__ query,
    const float* __restrict__ qpos, const ushort* __restrict__ Bt,
    const float* __restrict__ bias,
    ushort* __restrict__ Cv, float* __restrict__ C0, float* __restrict__ C1)
{
    __shared__ short As[64][40], Bhs[128][40];  // pad 32->40

    const int tid = threadIdx.x;

    // ---- T1: XCD-aware bijective remap [r13 proven] ----
    const int bid0 = blockIdx.x;
    int bid;
    if (bid0 < 1224) {
        bid = (bid0 & 7) * 153 + (bid0 >> 3);              // 1224 = 8*153
    } else {
        int q = bid0 - 1224;                               // 939 = 8*117+3
        int xcd = q & 7, idx = q >> 3;
        int orig = (xcd < 3) ? (xcd * 118 + idx)
                             : (3 * 118 + (xcd - 3) * 117 + idx);
        bid = 1224 + orig;
    }

    bool isval; int mblk, npan;
    if (bid < 1224) { isval = true;  mblk = bid >> 1; npan = bid & 1; }
    else { int q = bid - 1224; isval = false; mblk = q / 3; npan = q % 3; }

    const int M  = isval ? (BS * NV) : (BS * NQ);
    const int m0 = mblk * 64;
    const int n0 = npan * 128;
    const int nbase = (isval ? 0 : 256) + n0;

    const float* A = isval ? value : query;

    // A staging: thread t -> row t>>2 (0..63), k-chunk (t&3)*8 (8 of 32 k)
    const int arow = tid >> 2;
    const int acol = (tid & 3) * 8;
    const bool aval = (m0 + arow) < M;
    const float* Ap  = A    + (size_t)(m0 + arow) * 256 + acol;
    const float* A2p = qpos + (size_t)(m0 + arow) * 256 + acol;
    // B staging: thread t -> row t>>1 (0..127), k-half (t&1)*16 (16 of 32 k)
    const int brow = tid >> 1;
    const int bcol = (tid & 1) * 16;
    const ushort* Bp = Bt + (size_t)(nbase + brow) * 256 + bcol;

    const int lane = tid & 63, wave = tid >> 6;
    const int wrow = (wave >> 1) * 32, wcol = (wave & 1) * 64;
    const int lr = lane & 15, quad = lane >> 4, lk = quad * 8;

    f32x4 acc[2][4] = {};

    for (int k0 = 0; k0 < 256; k0 += 32) {
        // ---- A: fp32 (+qpos) -> bf16 staged to LDS (proven form) ----
        #pragma unroll
        for (int g = 0; g < 2; g++) {
            f32x4 v = {};
            if (aval) {
                v = *(const f32x4*)(Ap + k0 + g * 4);
                if (!isval) v += *(const f32x4*)(A2p + k0 + g * 4);
            }
            s16x4 hh;
            #pragma unroll
            for (int e = 0; e < 4; e++) hh[e] = (short)f2bf(v[e]);
            *(s16x4*)&As[arow][acol + g * 4] = hh;
        }
        // ---- B: bf16 vector copy, BOTH halves (16 shorts/thread) ----
        *(bf16x8*)&Bhs[brow][bcol]     = *(const bf16x8*)(Bp + k0);
        *(bf16x8*)&Bhs[brow][bcol + 8] = *(const bf16x8*)(Bp + k0 + 8);
        __syncthreads();

        bf16x8 af[2], bhf[4];
        #pragma unroll
        for (int i = 0; i < 2; i++)
            af[i] = *(const bf16x8*)&As[wrow + i * 16 + lr][lk];
        #pragma unroll
        for (int j = 0; j < 4; j++)
            bhf[j] = *(const bf16x8*)&Bhs[wcol + j * 16 + lr][lk];
        #pragma unroll
        for (int i = 0; i < 2; i++)
            #pragma unroll
            for (int j = 0; j < 4; j++)
                acc[i][j] = __builtin_amdgcn_mfma_f32_16x16x32_bf16(af[i], bhf[j], acc[i][j], 0, 0, 0);
        __syncthreads();
    }

    // ---- epilogue (proven mapping; value-plane store now fp16) ----
    #pragma unroll
    for (int j = 0; j < 4; j++) {
        int cc = wcol + j * 16 + lr;
        int col = n0 + cc;
        float bb = bias[nbase + cc];
        #pragma unroll
        for (int i = 0; i < 2; i++) {
            int gmb = m0 + wrow + i * 16 + quad * 4;
            #pragma unroll
            for (int r = 0; r < 4; r++) {
                int gm = gmb + r;
                if (gm < M) {
                    float val = acc[i][j][r] + bb;
                    if (isval) {
                        int h = col >> 5, d = col & 31;
                        int b = (gm >= NV) ? 1 : 0;
                        int pix = gm - b * NV;
                        Cv[((size_t)(b * 8 + h) * NV + pix) * 32 + d] =
                            __half_as_ushort(__float2half(val));
                    } else {
                        if (col < 256) C0[(size_t)gm * 256 + col] = val;
                        else           C1[(size_t)gm * 128 + (col - 256)] = val;
                    }
                }
            }
        }
    }
}

// ---------------------------------------------------------------------------
// Fused softmax + location + bilinear gather. [r14 partition PROVEN:
// 16 queries x 1 head, (b,h) in low 4 bits -> XCD-local value plane in L2.]
// ROUND-16 instruction-level trims (algorithm identical):
//  - value plane is fp16: decode = half2->float2 + fma (v_fma_mix path),
//    removing 32 shift/mask ops per ib (was the bf16 unpack).
//  - (offset, weight) packed into ONE int2 LDS array: 16 ds_read_b64/ib
//    instead of 32 ds_read_b32 (broadcast within 16-lane groups).
// ---------------------------------------------------------------------------
__global__ __launch_bounds__(256) void sample4(
    const ushort* __restrict__ v, const float* __restrict__ off,
    const float* __restrict__ attn, const float* __restrict__ refp,
    float* __restrict__ out)
{
    __shared__ int2 s_ow[256][4];   // .x = element offset, .y = weight bits

    const int t = threadIdx.x;
    const int combo = blockIdx.x & 15;     // (b, head) -> fixed XCD slot
    const int qgrp  = blockIdx.x >> 4;     // 0..624
    const int b  = combo & 1;
    const int h0 = combo >> 1;             // 0..7

    {
        const int qloc = t >> 4;           // 0..15
        const int lp   = t & 15;
        const int l = lp >> 2, p = lp & 3;
        const size_t bq = (size_t)b * NQ + qgrp * 16 + qloc;

        float logit = attn[bq * 128 + h0 * 16 + lp];
        float mx = logit;
        #pragma unroll
        for (int m = 1; m < 16; m <<= 1) mx = fmaxf(mx, __shfl_xor(mx, m, 16));
        float e = __expf(logit - mx);
        float s = e;
        #pragma unroll
        for (int m = 1; m < 16; m <<= 1) s += __shfl_xor(s, m, 16);
        float w = e / s;

        const float Wf[4] = {160.f, 80.f, 40.f, 20.f};
        const float Hf[4] = {92.f, 46.f, 23.f, 12.f};
        const int   Wi[4] = {160, 80, 40, 20};
        const int   Hi[4] = {92, 46, 23, 12};
        const int   st[4] = {0, 14720, 18400, 19320};

        float ox = off[bq * 256 + h0 * 32 + l * 8 + p * 2];
        float oy = off[bq * 256 + h0 * 32 + l * 8 + p * 2 + 1];
        float rx = refp[bq * 8 + p * 2];
        float ry = refp[bq * 8 + p * 2 + 1];
        float x = rx * Wf[l] + ox - 0.5f;
        float y = ry * Hf[l] + oy - 0.5f;
        float x0f = floorf(x), y0f = floorf(y);
        float wx1 = x - x0f, wy1 = y - y0f;
        float wx0 = 1.f - wx1, wy0 = 1.f - wy1;
        int x0 = (int)x0f, y0 = (int)y0f;
        const int W = Wi[l], H = Hi[l];
        float mx0 = ((unsigned)x0       < (unsigned)W) ? 1.f : 0.f;
        float mx1 = ((unsigned)(x0 + 1) < (unsigned)W) ? 1.f : 0.f;
        float my0 = ((unsigned)y0       < (unsigned)H) ? 1.f : 0.f;
        float my1 = ((unsigned)(y0 + 1) < (unsigned)H) ? 1.f : 0.f;
        int xc0 = min(max(x0, 0), W - 1);
        int xc1 = min(max(x0 + 1, 0), W - 1);
        int yc0 = min(max(y0, 0), H - 1);
        int yc1 = min(max(y0 + 1, 0), H - 1);
        int base = ((b * 8 + h0) * NV + st[l]) * 32;
        s_ow[t][0] = make_int2(base + (yc0 * W + xc0) * 32,
                               __float_as_int(w * wy0 * wx0 * my0 * mx0));
        s_ow[t][1] = make_int2(base + (yc0 * W + xc1) * 32,
                               __float_as_int(w * wy0 * wx1 * my0 * mx1));
        s_ow[t][2] = make_int2(base + (yc1 * W + xc0) * 32,
                               __float_as_int(w * wy1 * wx0 * my1 * mx0));
        s_ow[t][3] = make_int2(base + (yc1 * W + xc1) * 32,
                               __float_as_int(w * wy1 * wx1 * my1 * mx1));
    }
    __syncthreads();

    const int g = t >> 4;          // 0..15: qloc
    const int lane = t & 15;       // channel pair
    const size_t bq = (size_t)b * NQ + qgrp * 16 + g;
    const int d2 = lane * 2;
    const int pbase = g * 16;      // 16 points of this (q, h0)

    float acc0 = 0.f, acc1 = 0.f, acc2 = 0.f, acc3 = 0.f;
    #pragma unroll
    for (int ib = 0; ib < 4; ib++) {
        int o[16]; float wgt[16];
        #pragma unroll
        for (int pp = 0; pp < 4; pp++) {
            int idx = pbase + ib * 4 + pp;
            #pragma unroll
            for (int c = 0; c < 4; c++) {
                int2 ow = s_ow[idx][c];
                o[pp * 4 + c]   = ow.x;
                wgt[pp * 4 + c] = __int_as_float(ow.y);
            }
        }
        unsigned u[16];
        #pragma unroll
        for (int j = 0; j < 16; j++)
            u[j] = *(const unsigned*)(v + o[j] + d2);
        #pragma unroll
        for (int j = 0; j < 16; j += 2) {
            float2 fa = __half22float2(*(const __half2*)&u[j]);
            float2 fb = __half22float2(*(const __half2*)&u[j + 1]);
            acc0 += wgt[j]     * fa.x;
            acc1 += wgt[j]     * fa.y;
            acc2 += wgt[j + 1] * fb.x;
            acc3 += wgt[j + 1] * fb.y;
        }
    }
    float2 res = make_float2(acc0 + acc2, acc1 + acc3);
    *(float2*)(out + bq * 256 + h0 * 32 + d2) = res;
}

extern "C" void kernel_launch(void* const* d_in, const int* in_sizes, int n_in,
                              void* d_out, int out_size, void* d_ws, size_t ws_size,
                              hipStream_t stream) {
    const float* query     = (const float*)d_in[0];
    const float* value     = (const float*)d_in[1];
    const float* query_pos = (const float*)d_in[2];
    const float* refp      = (const float*)d_in[3];
    const float* W_val     = (const float*)d_in[4];
    const float* b_val     = (const float*)d_in[5];
    const float* W_off     = (const float*)d_in[6];
    const float* b_off     = (const float*)d_in[7];
    const float* W_attn    = (const float*)d_in[8];
    const float* b_attn    = (const float*)d_in[9];
    float* out = (float*)d_out;

    char* w = (char*)d_ws;
    float*  off    = (float*)w;   w += 20480000;   // 20000 x 256 fp32
    float*  attn   = (float*)w;   w += 10240000;   // 20000 x 128 fp32
    ushort* vp_bf  = (ushort*)w;  w += 20029440;   // planar (b,h,NV,32) fp16
    ushort* Bt     = (ushort*)w;  w += 327680;     // 640 x 256 bf16
    float*  bias_c = (float*)w;   w += 2560;

    convert_W<<<640, 256, 0, stream>>>(W_val, W_off, W_attn, b_val, b_off, b_attn,
                                       Bt, bias_c);

    // one dispatch: value-proj (1224 blocks) + query-proj (939 blocks)
    gemm_fused<<<1224 + 939, 256, 0, stream>>>(value, query, query_pos, Bt, bias_c,
                                               vp_bf, off, attn);

    // fused softmax + loc + bilinear sample: 16 queries x 1 head per block,
    // (b,h) in low 4 bits of blockIdx -> XCD-local value plane (1.25MB in L2)
    sample4<<<(BS * NQ / 16) * NH, 256, 0, stream>>>(vp_bf, off, attn, refp, out);
}

// Round 9
// 199.800 us; speedup vs baseline: 1.0821x; 1.0134x over previous
//
#include <hip/hip_runtime.h>
#include <hip/hip_fp16.h>

#define NQ 10000
#define BS 2
#define NV 19560
#define NH 8
#define HD 32
#define EMB 256

typedef __attribute__((ext_vector_type(8))) short bf16x8;
typedef __attribute__((ext_vector_type(8))) unsigned short u16x8;
typedef __attribute__((ext_vector_type(4))) float f32x4;
typedef __attribute__((ext_vector_type(4))) short s16x4;

__device__ __forceinline__ unsigned short f2bf(float x) {
    unsigned u = __float_as_uint(x);
    u += 0x7FFFu + ((u >> 16) & 1u);       // RNE
    return (unsigned short)(u >> 16);
}

// ---------------------------------------------------------------------------
// Transpose weights into Bt[n][k] bf16 + concat biases. [proven]
// ---------------------------------------------------------------------------
__global__ __launch_bounds__(256) void convert_W(
    const float* __restrict__ Wv, const float* __restrict__ Wo,
    const float* __restrict__ Wa, const float* __restrict__ bv,
    const float* __restrict__ bo, const float* __restrict__ ba,
    ushort* __restrict__ Bt, float* __restrict__ bias) {
    int n = blockIdx.x;      // 0..639
    int k = threadIdx.x;     // 0..255
    float x;
    if (n < 256)       x = Wv[k * 256 + n];
    else if (n < 512)  x = Wo[k * 256 + (n - 256)];
    else               x = Wa[k * 128 + (n - 512)];
    Bt[n * 256 + k] = f2bf(x);
    if (k == 0)
        bias[n] = (n < 256) ? bv[n] : (n < 512) ? bo[n - 256] : ba[n - 512];
}

// ---------------------------------------------------------------------------
// Fused GEMM. [FROZEN: r13 proven body (r9 2-barrier 64x128 + T1 remap) with
// fp16 Cv store. Ledger: r10 119 / r11 105 / r12 68 / r15 85 vs this 56.]
// ---------------------------------------------------------------------------
__global__ __launch_bounds__(256) void gemm_fused(
    const float* __restrict__ value, const float* __restrict__ query,
    const float* __restrict__ qpos, const ushort* __restrict__ Bt,
    const float* __restrict__ bias,
    ushort* __restrict__ Cv, float* __restrict__ C0, float* __restrict__ C1)
{
    __shared__ short As[64][40], Bhs[128][40];  // pad 32->40

    const int tid = threadIdx.x;

    // ---- T1: XCD-aware bijective remap [r13 proven] ----
    const int bid0 = blockIdx.x;
    int bid;
    if (bid0 < 1224) {
        bid = (bid0 & 7) * 153 + (bid0 >> 3);              // 1224 = 8*153
    } else {
        int q = bid0 - 1224;                               // 939 = 8*117+3
        int xcd = q & 7, idx = q >> 3;
        int orig = (xcd < 3) ? (xcd * 118 + idx)
                             : (3 * 118 + (xcd - 3) * 117 + idx);
        bid = 1224 + orig;
    }

    bool isval; int mblk, npan;
    if (bid < 1224) { isval = true;  mblk = bid >> 1; npan = bid & 1; }
    else { int q = bid - 1224; isval = false; mblk = q / 3; npan = q % 3; }

    const int M  = isval ? (BS * NV) : (BS * NQ);
    const int m0 = mblk * 64;
    const int n0 = npan * 128;
    const int nbase = (isval ? 0 : 256) + n0;

    const float* A = isval ? value : query;

    const int arow = tid >> 2;
    const int acol = (tid & 3) * 8;
    const bool aval = (m0 + arow) < M;
    const float* Ap  = A    + (size_t)(m0 + arow) * 256 + acol;
    const float* A2p = qpos + (size_t)(m0 + arow) * 256 + acol;
    const int brow = tid >> 1;
    const int bcol = (tid & 1) * 16;
    const ushort* Bp = Bt + (size_t)(nbase + brow) * 256 + bcol;

    const int lane = tid & 63, wave = tid >> 6;
    const int wrow = (wave >> 1) * 32, wcol = (wave & 1) * 64;
    const int lr = lane & 15, quad = lane >> 4, lk = quad * 8;

    f32x4 acc[2][4] = {};

    for (int k0 = 0; k0 < 256; k0 += 32) {
        #pragma unroll
        for (int g = 0; g < 2; g++) {
            f32x4 v = {};
            if (aval) {
                v = *(const f32x4*)(Ap + k0 + g * 4);
                if (!isval) v += *(const f32x4*)(A2p + k0 + g * 4);
            }
            s16x4 hh;
            #pragma unroll
            for (int e = 0; e < 4; e++) hh[e] = (short)f2bf(v[e]);
            *(s16x4*)&As[arow][acol + g * 4] = hh;
        }
        *(bf16x8*)&Bhs[brow][bcol]     = *(const bf16x8*)(Bp + k0);
        *(bf16x8*)&Bhs[brow][bcol + 8] = *(const bf16x8*)(Bp + k0 + 8);
        __syncthreads();

        bf16x8 af[2], bhf[4];
        #pragma unroll
        for (int i = 0; i < 2; i++)
            af[i] = *(const bf16x8*)&As[wrow + i * 16 + lr][lk];
        #pragma unroll
        for (int j = 0; j < 4; j++)
            bhf[j] = *(const bf16x8*)&Bhs[wcol + j * 16 + lr][lk];
        #pragma unroll
        for (int i = 0; i < 2; i++)
            #pragma unroll
            for (int j = 0; j < 4; j++)
                acc[i][j] = __builtin_amdgcn_mfma_f32_16x16x32_bf16(af[i], bhf[j], acc[i][j], 0, 0, 0);
        __syncthreads();
    }

    #pragma unroll
    for (int j = 0; j < 4; j++) {
        int cc = wcol + j * 16 + lr;
        int col = n0 + cc;
        float bb = bias[nbase + cc];
        #pragma unroll
        for (int i = 0; i < 2; i++) {
            int gmb = m0 + wrow + i * 16 + quad * 4;
            #pragma unroll
            for (int r = 0; r < 4; r++) {
                int gm = gmb + r;
                if (gm < M) {
                    float val = acc[i][j][r] + bb;
                    if (isval) {
                        int h = col >> 5, d = col & 31;
                        int b = (gm >= NV) ? 1 : 0;
                        int pix = gm - b * NV;
                        Cv[((size_t)(b * 8 + h) * NV + pix) * 32 + d] =
                            __half_as_ushort(__float2half(val));
                    } else {
                        if (col < 256) C0[(size_t)gm * 256 + col] = val;
                        else           C1[(size_t)gm * 128 + (col - 256)] = val;
                    }
                }
            }
        }
    }
}

// ---------------------------------------------------------------------------
// Fused softmax + location + bilinear gather. ROUND-17 REPARTITION:
// block = 64 queries x ONE head, thread (q = t>>2, l = t&3).
// r16 null proved payload-FMA isn't the cost (~4us total); the cost is
// PER-LOAD overhead (addr chains, issue, LDS offset reads). Gather payload
// per corner is a full 64B line (32ch fp16) -> fetch it with 4 lanes x 16B
// dwordx4 instead of 16 lanes x 4B: global-load instrs, addr ops, and LDS
// offset-reads all /4 at identical coalescing (4x16B = one line).
// Phase 1: thread l owns level l's 4 points (level constants uniform/thread,
// no LUT scratch); softmax = 4 local + 2-step width-4 shuffle.
// LDS s_ow[64][65] int2: q-stride 65*8B = 130 dwords = 2 mod 32 -> 16 q's of
// a wave hit 16 distinct bank-pairs on ds_read_b64 (conflict-free); 4 lanes
// of a q read the same addr (broadcast). XCD pinning kept: (b,h) = low 4
// bits of blockIdx -> one value plane (1.25MB) per XCD L2 [r14 proven].
// ---------------------------------------------------------------------------
__global__ __launch_bounds__(256) void sample4(
    const ushort* __restrict__ v, const float* __restrict__ off,
    const float* __restrict__ attn, const float* __restrict__ refp,
    float* __restrict__ out)
{
    __shared__ int2 s_ow[64][65];   // [q][pt*4+c], pad to 65

    const int t = threadIdx.x;
    const int combo = blockIdx.x & 15;     // (b, head) -> fixed XCD slot
    const int qgrp  = blockIdx.x >> 4;     // 0..156
    const int b  = combo & 1;
    const int h0 = combo >> 1;             // 0..7

    const int q = t >> 2;                  // 0..63
    const int l = t & 3;                   // level owned by this thread
    const int qt = qgrp * 64 + q;
    const bool valid = qt < NQ;
    const size_t bq = (size_t)b * NQ + (valid ? qt : NQ - 1);

    {
        // ---- softmax over this (q,h): 4 local points + width-4 shuffle ----
        f32x4 lg = *(const f32x4*)(attn + bq * 128 + h0 * 16 + l * 4);
        float mx = fmaxf(fmaxf(lg[0], lg[1]), fmaxf(lg[2], lg[3]));
        mx = fmaxf(mx, __shfl_xor(mx, 1, 4));
        mx = fmaxf(mx, __shfl_xor(mx, 2, 4));
        float e0 = __expf(lg[0] - mx), e1 = __expf(lg[1] - mx);
        float e2 = __expf(lg[2] - mx), e3 = __expf(lg[3] - mx);
        float s = e0 + e1 + e2 + e3;
        s += __shfl_xor(s, 1, 4);
        s += __shfl_xor(s, 2, 4);
        float inv = 1.f / s;

        // ---- level constants: uniform per thread (no indexed LUT) ----
        const float Wl = (l == 0) ? 160.f : (l == 1) ? 80.f : (l == 2) ? 40.f : 20.f;
        const float Hl = (l == 0) ? 92.f  : (l == 1) ? 46.f : (l == 2) ? 23.f : 12.f;
        const int  stl = (l == 0) ? 0 : (l == 1) ? 14720 : (l == 2) ? 18400 : 19320;
        const int  Wi_ = (int)Wl, Hi_ = (int)Hl;
        const int base = ((b * 8 + h0) * NV + stl) * 32;

        f32x4 of0 = *(const f32x4*)(off + bq * 256 + h0 * 32 + l * 8);
        f32x4 of1 = *(const f32x4*)(off + bq * 256 + h0 * 32 + l * 8 + 4);
        f32x4 r0  = *(const f32x4*)(refp + bq * 8);
        f32x4 r1  = *(const f32x4*)(refp + bq * 8 + 4);

        float ws[4]  = {e0 * inv, e1 * inv, e2 * inv, e3 * inv};
        float oxs[4] = {of0[0], of0[2], of1[0], of1[2]};
        float oys[4] = {of0[1], of0[3], of1[1], of1[3]};
        float rxs[4] = {r0[0], r0[2], r1[0], r1[2]};
        float rys[4] = {r0[1], r0[3], r1[1], r1[3]};

        #pragma unroll
        for (int p = 0; p < 4; p++) {
            float x = rxs[p] * Wl + oxs[p] - 0.5f;
            float y = rys[p] * Hl + oys[p] - 0.5f;
            float x0f = floorf(x), y0f = floorf(y);
            float wx1 = x - x0f, wy1 = y - y0f;
            float wx0 = 1.f - wx1, wy0 = 1.f - wy1;
            int x0 = (int)x0f, y0 = (int)y0f;
            float mx0 = ((unsigned)x0       < (unsigned)Wi_) ? 1.f : 0.f;
            float mx1 = ((unsigned)(x0 + 1) < (unsigned)Wi_) ? 1.f : 0.f;
            float my0 = ((unsigned)y0       < (unsigned)Hi_) ? 1.f : 0.f;
            float my1 = ((unsigned)(y0 + 1) < (unsigned)Hi_) ? 1.f : 0.f;
            int xc0 = min(max(x0, 0), Wi_ - 1);
            int xc1 = min(max(x0 + 1, 0), Wi_ - 1);
            int yc0 = min(max(y0, 0), Hi_ - 1);
            int yc1 = min(max(y0 + 1, 0), Hi_ - 1);
            float w = ws[p];
            int pt4 = (l * 4 + p) * 4;
            s_ow[q][pt4 + 0] = make_int2(base + (yc0 * Wi_ + xc0) * 32,
                                         __float_as_int(w * wy0 * wx0 * my0 * mx0));
            s_ow[q][pt4 + 1] = make_int2(base + (yc0 * Wi_ + xc1) * 32,
                                         __float_as_int(w * wy0 * wx1 * my0 * mx1));
            s_ow[q][pt4 + 2] = make_int2(base + (yc1 * Wi_ + xc0) * 32,
                                         __float_as_int(w * wy1 * wx0 * my1 * mx0));
            s_ow[q][pt4 + 3] = make_int2(base + (yc1 * Wi_ + xc1) * 32,
                                         __float_as_int(w * wy1 * wx1 * my1 * mx1));
        }
    }
    __syncthreads();

    // ---- phase 2: 4 lanes per q, 16B (8ch) per lane per corner ----
    const int d8 = l * 8;                  // this lane's 8 channels
    const ushort* vb = v + d8;

    float a0 = 0.f, a1 = 0.f, a2 = 0.f, a3 = 0.f;
    float a4 = 0.f, a5 = 0.f, a6 = 0.f, a7 = 0.f;

    #pragma unroll
    for (int bt = 0; bt < 8; bt++) {       // 2 points per batch
        int2 ow[8];
        #pragma unroll
        for (int pp = 0; pp < 2; pp++)
            #pragma unroll
            for (int c = 0; c < 4; c++)
                ow[pp * 4 + c] = s_ow[q][(bt * 2 + pp) * 4 + c];

        u16x8 u[8];
        #pragma unroll
        for (int i = 0; i < 8; i++)
            u[i] = *(const u16x8*)(vb + ow[i].x);

        #pragma unroll
        for (int i = 0; i < 8; i++) {
            float w = __int_as_float(ow[i].y);
            const __half2* hp = (const __half2*)&u[i];
            float2 f0 = __half22float2(hp[0]);
            float2 f1 = __half22float2(hp[1]);
            float2 f2 = __half22float2(hp[2]);
            float2 f3 = __half22float2(hp[3]);
            a0 += w * f0.x; a1 += w * f0.y;
            a2 += w * f1.x; a3 += w * f1.y;
            a4 += w * f2.x; a5 += w * f2.y;
            a6 += w * f3.x; a7 += w * f3.y;
        }
    }

    if (valid) {
        float* op = out + bq * 256 + h0 * 32 + d8;
        f32x4 o0 = {a0, a1, a2, a3}, o1 = {a4, a5, a6, a7};
        *(f32x4*)op       = o0;
        *(f32x4*)(op + 4) = o1;
    }
}

extern "C" void kernel_launch(void* const* d_in, const int* in_sizes, int n_in,
                              void* d_out, int out_size, void* d_ws, size_t ws_size,
                              hipStream_t stream) {
    const float* query     = (const float*)d_in[0];
    const float* value     = (const float*)d_in[1];
    const float* query_pos = (const float*)d_in[2];
    const float* refp      = (const float*)d_in[3];
    const float* W_val     = (const float*)d_in[4];
    const float* b_val     = (const float*)d_in[5];
    const float* W_off     = (const float*)d_in[6];
    const float* b_off     = (const float*)d_in[7];
    const float* W_attn    = (const float*)d_in[8];
    const float* b_attn    = (const float*)d_in[9];
    float* out = (float*)d_out;

    char* w = (char*)d_ws;
    float*  off    = (float*)w;   w += 20480000;   // 20000 x 256 fp32
    float*  attn   = (float*)w;   w += 10240000;   // 20000 x 128 fp32
    ushort* vp_bf  = (ushort*)w;  w += 20029440;   // planar (b,h,NV,32) fp16
    ushort* Bt     = (ushort*)w;  w += 327680;     // 640 x 256 bf16
    float*  bias_c = (float*)w;   w += 2560;

    convert_W<<<640, 256, 0, stream>>>(W_val, W_off, W_attn, b_val, b_off, b_attn,
                                       Bt, bias_c);

    // one dispatch: value-proj (1224 blocks) + query-proj (939 blocks)
    gemm_fused<<<1224 + 939, 256, 0, stream>>>(value, query, query_pos, Bt, bias_c,
                                               vp_bf, off, attn);

    // 64 queries x 1 head per block; 157 q-groups x 16 (b,h) combos
    sample4<<<157 * 16, 256, 0, stream>>>(vp_bf, off, attn, refp, out);
}